// Round 7
// baseline (378.303 us; speedup 1.0000x reference)
//
#include <hip/hip_runtime.h>
#include <hip/hip_bf16.h>
#include <stdint.h>

#define CHUNKC 32
#define PRIORC 64
#define POSEC 512
#define PREDC 128
#define NB 2048
#define K1 (CHUNKC*POSEC)   // 16384
#define NCOPY 768           // copy blocks in fused kernel

typedef __attribute__((ext_vector_type(8))) short bf16x8;
typedef __attribute__((ext_vector_type(4))) float f32x4;
typedef __attribute__((ext_vector_type(4))) float f4v;
typedef __attribute__((ext_vector_type(4))) unsigned short u16x4;

__device__ __forceinline__ unsigned short f2b(float f) {
    union { float f; unsigned int u; } x; x.f = f;
    unsigned int r = x.u + 0x7fffu + ((x.u >> 16) & 1u);
    return (unsigned short)(r >> 16);
}

__device__ __forceinline__ void gload_lds16(const void* g, void* l) {
    __builtin_amdgcn_global_load_lds(
        (const __attribute__((address_space(1))) unsigned int*)g,
        (__attribute__((address_space(3))) unsigned int*)l, 16, 0, 0);
}

// ---------------- cvt_all: x-slice, W1, W2 -> bf16 ----------------
#define XN4   8388608   // 2048*4096 float4 of x-slice
#define W1N4  2097152   // 512*16384/4
#define W2N4  65536     // 512*512/4
__global__ __launch_bounds__(256) void cvt_all_kernel(const f4v* __restrict__ init,
                                                      const f4v* __restrict__ W1,
                                                      const f4v* __restrict__ W2,
                                                      u16x4* __restrict__ xb,
                                                      u16x4* __restrict__ w1b,
                                                      u16x4* __restrict__ w2b) {
    const int64_t n = XN4 + W1N4 + W2N4;
    const int64_t stride = (int64_t)gridDim.x * blockDim.x;
    for (int64_t i = (int64_t)blockIdx.x * blockDim.x + threadIdx.x; i < n; i += stride) {
        f4v v; u16x4* dst;
        if (i < XN4) {
            int64_t b = i >> 12, r = i & 4095;
            v = __builtin_nontemporal_load(init + b * 8192 + 4096 + r);
            dst = xb + i;
        } else if (i < XN4 + W1N4) {
            v = __builtin_nontemporal_load(W1 + (i - XN4));
            dst = w1b + (i - XN4);
        } else {
            v = __builtin_nontemporal_load(W2 + (i - XN4 - W1N4));
            dst = w2b + (i - XN4 - W1N4);
        }
        u16x4 o;
        o[0] = f2b(v[0]); o[1] = f2b(v[1]); o[2] = f2b(v[2]); o[3] = f2b(v[3]);
        __builtin_nontemporal_store(o, dst);
    }
}

// ---------------- fused: GEMM1 partials + tail copy ----------------
// Blocks 0..NG-1 (NG=16*KS, dispatched FIRST -> co-resident 1/CU): 256x256-tile
// split-K GEMM, 8 waves, gload_lds both operands, XCD-chunked swizzle.
// Blocks NG..NG+767: stream pred[:,32:128,:] -> out (805 MB) concurrently;
// the GEMM's MFMA hides under this HBM stream (work per CU balanced either way).
template<int KSv>
__global__ __launch_bounds__(512) void gemm1_copy_kernel(const ushort* __restrict__ xb,
                                                         const ushort* __restrict__ w1b,
                                                         float* __restrict__ part,
                                                         const f4v* __restrict__ pred4,
                                                         f4v* __restrict__ out4) {
    __shared__ ushort As[256][64];   // 32 KB, linear (global_load_lds)
    __shared__ ushort Bs[256][64];   // 32 KB
    const int NG = 16 * KSv;
    const int t = threadIdx.x;

    if ((int)blockIdx.x >= NG) {
        // ---- copy path: tail rows 32..127 of pred -> out ----
        // total 25,165,824 float4; 768 blocks * 512 thr * 64 iters.
        // step = 768*512 = 393216 f4 = exactly 32 batches -> idx += 32*16384.
        const int cid = blockIdx.x - NG;
        int64_t j0 = (int64_t)cid * 512 + t;            // < 393216
        int b0 = (int)(j0 / 12288);
        int rem = (int)(j0 - (int64_t)b0 * 12288);
        int64_t idx = (int64_t)b0 * 16384 + 4096 + rem;
#pragma unroll 4
        for (int it = 0; it < 64; ++it) {
            f4v h = __builtin_nontemporal_load(pred4 + idx);
            __builtin_nontemporal_store(h, out4 + idx);
            idx += 524288;                               // 32 batches * 16384
        }
        return;
    }

    // ---- GEMM path (round-6 256x256 structure) ----
    const int l = t & 63, wid = t >> 6;
    const int wr = wid >> 2, wc = wid & 3;          // 2x4 waves; wave owns 128x64
    const int cpx = NG >> 3;                        // blocks per XCD chunk
    const int orig = (blockIdx.x & 7) * cpx + (blockIdx.x >> 3);
    const int mt = orig & 7, nt = (orig >> 3) & 1, ks = orig >> 4;
    const int KCHv = K1 / KSv;

    f32x4 acc[8][4] = {};

    const ushort* aG = xb  + (int64_t)(mt * 256) * K1 + ks * KCHv;
    const ushort* bG = w1b + (int64_t)(nt * 256) * K1 + ks * KCHv;
    const int srow = t >> 3, scol = (t & 7) * 8;

    const int fr = l & 15, fq = l >> 4;

    for (int k0 = 0; k0 < KCHv; k0 += 64) {
#pragma unroll
        for (int i = 0; i < 4; ++i) {
            gload_lds16(aG + (int64_t)(i * 64 + srow) * K1 + k0 + scol,
                        (char*)&As[0][0] + i * 8192 + wid * 1024);
            gload_lds16(bG + (int64_t)(i * 64 + srow) * K1 + k0 + scol,
                        (char*)&Bs[0][0] + i * 8192 + wid * 1024);
        }
        __syncthreads();
#pragma unroll
        for (int k2 = 0; k2 < 2; ++k2) {
            bf16x8 a[8], b[4];
#pragma unroll
            for (int m = 0; m < 8; ++m)
                a[m] = *(const bf16x8*)&As[wr * 128 + m * 16 + fr][k2 * 32 + fq * 8];
#pragma unroll
            for (int n = 0; n < 4; ++n)
                b[n] = *(const bf16x8*)&Bs[wc * 64 + n * 16 + fr][k2 * 32 + fq * 8];
#pragma unroll
            for (int m = 0; m < 8; ++m)
#pragma unroll
                for (int n = 0; n < 4; ++n)
                    acc[m][n] = __builtin_amdgcn_mfma_f32_16x16x32_bf16(a[m], b[n], acc[m][n], 0, 0, 0);
        }
        __syncthreads();
    }

    float* P = part + (int64_t)ks * NB * POSEC;
    const int mbase = mt * 256 + wr * 128, nbase = nt * 256 + wc * 64;
#pragma unroll
    for (int m = 0; m < 8; ++m)
#pragma unroll
        for (int n = 0; n < 4; ++n) {
            int row0 = mbase + m * 16 + fq * 4;
            int col  = nbase + n * 16 + fr;
#pragma unroll
            for (int r = 0; r < 4; ++r)
                P[(int64_t)(row0 + r) * POSEC + col] = acc[m][n][r];
        }
}

// ---------------- reduce: A2 = bf16(sum_ks part + b1) ----------------
template<int KSv>
__global__ __launch_bounds__(256) void reduce_kernel(const float4* __restrict__ part,
                                                     const float* __restrict__ b1,
                                                     ushort4* __restrict__ A2) {
    const int i4 = blockIdx.x * 256 + threadIdx.x;      // 262144 float4 total
    float4 s = part[i4];
#pragma unroll
    for (int k = 1; k < KSv; ++k) {
        float4 p = part[(int64_t)k * 262144 + i4];
        s.x += p.x; s.y += p.y; s.z += p.z; s.w += p.w;
    }
    const int col = (i4 * 4) & 511;
    float4 bv = *(const float4*)&b1[col];
    A2[i4] = make_ushort4(f2b(s.x + bv.x), f2b(s.y + bv.y), f2b(s.z + bv.z), f2b(s.w + bv.w));
}

// ---------------- GEMM2: mem = A2 @ W2b^T + b2 ----------------
__global__ __launch_bounds__(256) void gemm2_kernel(const ushort* __restrict__ A2,
                                                    const ushort* __restrict__ w2b,
                                                    const float* __restrict__ b2,
                                                    float* __restrict__ mem) {
    __shared__ ushort As[64][64];
    __shared__ ushort Bs[64][64];
    const int t = threadIdx.x;
    const int l = t & 63, wid = t >> 6;
    const int wr = wid >> 1, wc = wid & 1;
    const int mt = blockIdx.x >> 3, nt = blockIdx.x & 7;

    f32x4 acc[2][2] = {};
    const ushort* aG = A2  + (int64_t)(mt * 64) * POSEC;
    const ushort* bG = w2b + (int64_t)(nt * 64) * POSEC;
    const int srow = t >> 3, scol = (t & 7) * 8;
    const int fr = l & 15, fq = l >> 4;

    for (int k0 = 0; k0 < POSEC; k0 += 64) {
#pragma unroll
        for (int i = 0; i < 2; ++i) {
            gload_lds16(aG + (int64_t)(i * 32 + srow) * POSEC + k0 + scol,
                        (char*)&As[0][0] + i * 4096 + wid * 1024);
            gload_lds16(bG + (int64_t)(i * 32 + srow) * POSEC + k0 + scol,
                        (char*)&Bs[0][0] + i * 4096 + wid * 1024);
        }
        __syncthreads();
#pragma unroll
        for (int k2 = 0; k2 < 2; ++k2) {
            bf16x8 a[2], b[2];
#pragma unroll
            for (int m = 0; m < 2; ++m)
                a[m] = *(const bf16x8*)&As[wr * 32 + m * 16 + fr][k2 * 32 + fq * 8];
#pragma unroll
            for (int n = 0; n < 2; ++n)
                b[n] = *(const bf16x8*)&Bs[wc * 32 + n * 16 + fr][k2 * 32 + fq * 8];
#pragma unroll
            for (int m = 0; m < 2; ++m)
#pragma unroll
                for (int n = 0; n < 2; ++n)
                    acc[m][n] = __builtin_amdgcn_mfma_f32_16x16x32_bf16(a[m], b[n], acc[m][n], 0, 0, 0);
        }
        __syncthreads();
    }

    const int mbase = mt * 64 + wr * 32, nbase = nt * 64 + wc * 32;
#pragma unroll
    for (int m = 0; m < 2; ++m)
#pragma unroll
        for (int n = 0; n < 2; ++n) {
            int row0 = mbase + m * 16 + fq * 4;
            int col  = nbase + n * 16 + fr;
            float bias = b2[col];
#pragma unroll
            for (int r = 0; r < 4; ++r)
                mem[(int64_t)(row0 + r) * POSEC + col] = acc[m][n][r] + bias;
        }
}

// ---------------- blend head: score + sigmoid + blend rows 0..31 ----------------
__global__ __launch_bounds__(256) void blend_head_kernel(const float* __restrict__ pred,
                                                         const float* __restrict__ mem,
                                                         float* __restrict__ out) {
    const int b = blockIdx.x;
    const int t = threadIdx.x;
    __shared__ float sm[POSEC];
    __shared__ float sg[CHUNKC];

    sm[t]       = mem[(int64_t)b * POSEC + t];
    sm[t + 256] = mem[(int64_t)b * POSEC + 256 + t];
    __syncthreads();

    const int l = t & 63, wid = t >> 6;
    const float4* sm4 = (const float4*)sm;
    const float4* p4 = (const float4*)pred + (int64_t)b * 16384;
    float4* o4 = (float4*)out + (int64_t)b * 16384;

#pragma unroll
    for (int ci = 0; ci < 8; ++ci) {
        int c = wid * 8 + ci;
        float4 h0 = p4[c * 128 + l * 2];
        float4 h1 = p4[c * 128 + l * 2 + 1];
        float4 m0 = sm4[l * 2];
        float4 m1 = sm4[l * 2 + 1];
        float s = h0.x * m0.x + h0.y * m0.y + h0.z * m0.z + h0.w * m0.w
                + h1.x * m1.x + h1.y * m1.y + h1.z * m1.z + h1.w * m1.w;
#pragma unroll
        for (int o = 32; o; o >>= 1) s += __shfl_xor(s, o);
        if (l == 0) sg[c] = 1.0f / (1.0f + expf(-s));
    }
    __syncthreads();

#pragma unroll
    for (int i = 0; i < 16; ++i) {
        int idx = i * 256 + t;
        int row = idx >> 7, c4 = idx & 127;
        float g = sg[row];
        float4 h = p4[idx];
        float4 m = sm4[c4];
        float4 r;
        r.x = g * h.x + (1.0f - g) * m.x;
        r.y = g * h.y + (1.0f - g) * m.y;
        r.z = g * h.z + (1.0f - g) * m.z;
        r.w = g * h.w + (1.0f - g) * m.w;
        o4[idx] = r;
    }
}

// ---------------- launch ----------------

extern "C" void kernel_launch(void* const* d_in, const int* in_sizes, int n_in,
                              void* d_out, int out_size, void* d_ws, size_t ws_size,
                              hipStream_t stream) {
    const float* init = (const float*)d_in[0];
    const float* pred = (const float*)d_in[1];
    const float* W1   = (const float*)d_in[2];
    const float* b1   = (const float*)d_in[3];
    const float* W2   = (const float*)d_in[4];
    const float* b2   = (const float*)d_in[5];
    float* out = (float*)d_out;

    // KS=16 needs 157,810,688 B of ws; fall back to KS=8 (124,256,256 B) if short.
    const int KS = (ws_size >= 157810688u) ? 16 : 8;

    char* ws = (char*)d_ws;
    ushort* xb   = (ushort*)(ws);                               // 67108864 B
    ushort* w1b  = (ushort*)(ws + 67108864);                    // 16777216 B
    ushort* w2b  = (ushort*)(ws + 83886080);                    //   524288 B
    float*  part = (float*) (ws + 84410368);                    // KS*4194304 B
    char*   after = ws + 84410368 + (size_t)KS * 4194304;
    ushort* A2   = (ushort*)(after);                            //  2097152 B
    float*  mem  = (float*) (after + 2097152);                  //  4194304 B

    cvt_all_kernel<<<2560, 256, 0, stream>>>((const f4v*)init, (const f4v*)W1,
                                             (const f4v*)W2,
                                             (u16x4*)xb, (u16x4*)w1b, (u16x4*)w2b);
    if (KS == 16) {
        gemm1_copy_kernel<16><<<256 + NCOPY, 512, 0, stream>>>(xb, w1b, part,
                                                               (const f4v*)pred, (f4v*)out);
        reduce_kernel<16><<<1024, 256, 0, stream>>>((const float4*)part, b1, (ushort4*)A2);
    } else {
        gemm1_copy_kernel<8><<<128 + NCOPY, 512, 0, stream>>>(xb, w1b, part,
                                                              (const f4v*)pred, (f4v*)out);
        reduce_kernel<8><<<1024, 256, 0, stream>>>((const float4*)part, b1, (ushort4*)A2);
    }
    gemm2_kernel<<<256, 256, 0, stream>>>(A2, w2b, b2, mem);
    blend_head_kernel<<<NB, 256, 0, stream>>>(pred, mem, out);
}

// Round 8
// 329.645 us; speedup vs baseline: 1.1476x; 1.1476x over previous
//
#include <hip/hip_runtime.h>
#include <hip/hip_bf16.h>
#include <stdint.h>

#define CHUNKC 32
#define PRIORC 64
#define POSEC 512
#define PREDC 128
#define NB 2048
#define K1 (CHUNKC*POSEC)   // 16384

typedef __attribute__((ext_vector_type(8))) short bf16x8;
typedef __attribute__((ext_vector_type(4))) float f32x4;
typedef __attribute__((ext_vector_type(4))) float f4v;
typedef __attribute__((ext_vector_type(4))) unsigned short u16x4;

__device__ __forceinline__ unsigned short f2b(float f) {
    union { float f; unsigned int u; } x; x.f = f;
    unsigned int r = x.u + 0x7fffu + ((x.u >> 16) & 1u);
    return (unsigned short)(r >> 16);
}

__device__ __forceinline__ void gload_lds16(const void* g, void* l) {
    __builtin_amdgcn_global_load_lds(
        (const __attribute__((address_space(1))) unsigned int*)g,
        (__attribute__((address_space(3))) unsigned int*)l, 16, 0, 0);
}

// ---------------- cvt_all: x-slice, W1, W2 -> bf16 (nontemporal streams) ----------------
#define XN4   8388608   // 2048*4096 float4 of x-slice
#define W1N4  2097152   // 512*16384/4
#define W2N4  65536     // 512*512/4
__global__ __launch_bounds__(256) void cvt_all_kernel(const f4v* __restrict__ init,
                                                      const f4v* __restrict__ W1,
                                                      const f4v* __restrict__ W2,
                                                      u16x4* __restrict__ xb,
                                                      u16x4* __restrict__ w1b,
                                                      u16x4* __restrict__ w2b) {
    const int64_t n = XN4 + W1N4 + W2N4;
    const int64_t stride = (int64_t)gridDim.x * blockDim.x;
    for (int64_t i = (int64_t)blockIdx.x * blockDim.x + threadIdx.x; i < n; i += stride) {
        f4v v; u16x4* dst;
        if (i < XN4) {
            int64_t b = i >> 12, r = i & 4095;
            v = __builtin_nontemporal_load(init + b * 8192 + 4096 + r);
            dst = xb + i;
        } else if (i < XN4 + W1N4) {
            v = __builtin_nontemporal_load(W1 + (i - XN4));
            dst = w1b + (i - XN4);
        } else {
            v = __builtin_nontemporal_load(W2 + (i - XN4 - W1N4));
            dst = w2b + (i - XN4 - W1N4);
        }
        u16x4 o;
        o[0] = f2b(v[0]); o[1] = f2b(v[1]); o[2] = f2b(v[2]); o[3] = f2b(v[3]);
        __builtin_nontemporal_store(o, dst);
    }
}

// ---------------- GEMM1: partials of x @ W1^T ----------------
// 256x256 tile, BK=64, 8 waves (2x4; wave owns 128x64), gload_lds both operands.
// T3-minimum 2-phase pipeline: double-buffered LDS (128 KB), ONE barrier/iter at
// the top (its vmcnt(0) drains loads that had a full iteration of latency cover),
// STAGE(next) issued right after the barrier.
// grid = 8 mt * 2 nt * KS ks; XCD-chunked bijective swizzle (grid % 8 == 0).
template<int KSv>
__global__ __launch_bounds__(512) void gemm1_kernel(const ushort* __restrict__ xb,
                                                    const ushort* __restrict__ w1b,
                                                    float* __restrict__ part) {
    __shared__ ushort As[2][256][64];   // 2 x 32 KB
    __shared__ ushort Bs[2][256][64];   // 2 x 32 KB
    const int t = threadIdx.x;
    const int l = t & 63, wid = t >> 6;
    const int wr = wid >> 2, wc = wid & 3;          // 2x4 waves; wave owns 128x64
    const int NG = 16 * KSv;
    const int cpx = NG >> 3;                        // blocks per XCD chunk
    const int orig = (blockIdx.x & 7) * cpx + (blockIdx.x >> 3);
    const int mt = orig & 7, nt = (orig >> 3) & 1, ks = orig >> 4;
    const int KCHv = K1 / KSv;
    const int NIT = KCHv / 64;

    f32x4 acc[8][4] = {};

    const ushort* aG = xb  + (int64_t)(mt * 256) * K1 + ks * KCHv;
    const ushort* bG = w1b + (int64_t)(nt * 256) * K1 + ks * KCHv;
    const int srow = t >> 3, scol = (t & 7) * 8;    // 64 rows x 8 cols of 16B per chunk

    const int fr = l & 15, fq = l >> 4;

    // prologue: stage tile 0 into buffer 0
#pragma unroll
    for (int i = 0; i < 4; ++i) {
        gload_lds16(aG + (int64_t)(i * 64 + srow) * K1 + scol,
                    (char*)&As[0][0][0] + i * 8192 + wid * 1024);
        gload_lds16(bG + (int64_t)(i * 64 + srow) * K1 + scol,
                    (char*)&Bs[0][0][0] + i * 8192 + wid * 1024);
    }

    for (int it = 0; it < NIT; ++it) {
        const int cur = it & 1;
        __syncthreads();    // drains buf[cur]'s loads (issued one full iter ago)
        if (it + 1 < NIT) { // stage next tile into the other buffer (read last iter,
                            // all its readers passed the barrier above)
            const int nxt = cur ^ 1;
            const int k0 = (it + 1) * 64;
#pragma unroll
            for (int i = 0; i < 4; ++i) {
                gload_lds16(aG + (int64_t)(i * 64 + srow) * K1 + k0 + scol,
                            (char*)&As[nxt][0][0] + i * 8192 + wid * 1024);
                gload_lds16(bG + (int64_t)(i * 64 + srow) * K1 + k0 + scol,
                            (char*)&Bs[nxt][0][0] + i * 8192 + wid * 1024);
            }
        }
#pragma unroll
        for (int k2 = 0; k2 < 2; ++k2) {
            bf16x8 a[8], b[4];
#pragma unroll
            for (int m = 0; m < 8; ++m)
                a[m] = *(const bf16x8*)&As[cur][wr * 128 + m * 16 + fr][k2 * 32 + fq * 8];
#pragma unroll
            for (int n = 0; n < 4; ++n)
                b[n] = *(const bf16x8*)&Bs[cur][wc * 64 + n * 16 + fr][k2 * 32 + fq * 8];
#pragma unroll
            for (int m = 0; m < 8; ++m)
#pragma unroll
                for (int n = 0; n < 4; ++n)
                    acc[m][n] = __builtin_amdgcn_mfma_f32_16x16x32_bf16(a[m], b[n], acc[m][n], 0, 0, 0);
        }
    }

    float* P = part + (int64_t)ks * NB * POSEC;
    const int mbase = mt * 256 + wr * 128, nbase = nt * 256 + wc * 64;
#pragma unroll
    for (int m = 0; m < 8; ++m)
#pragma unroll
        for (int n = 0; n < 4; ++n) {
            int row0 = mbase + m * 16 + fq * 4;
            int col  = nbase + n * 16 + fr;
#pragma unroll
            for (int r = 0; r < 4; ++r)
                P[(int64_t)(row0 + r) * POSEC + col] = acc[m][n][r];
        }
}

// ---------------- reduce: A2 = bf16(sum_ks part + b1) ----------------
template<int KSv>
__global__ __launch_bounds__(256) void reduce_kernel(const float4* __restrict__ part,
                                                     const float* __restrict__ b1,
                                                     ushort4* __restrict__ A2) {
    const int i4 = blockIdx.x * 256 + threadIdx.x;      // 262144 float4 total
    float4 s = part[i4];
#pragma unroll
    for (int k = 1; k < KSv; ++k) {
        float4 p = part[(int64_t)k * 262144 + i4];
        s.x += p.x; s.y += p.y; s.z += p.z; s.w += p.w;
    }
    const int col = (i4 * 4) & 511;
    float4 bv = *(const float4*)&b1[col];
    A2[i4] = make_ushort4(f2b(s.x + bv.x), f2b(s.y + bv.y), f2b(s.z + bv.z), f2b(s.w + bv.w));
}

// ---------------- GEMM2: mem = A2 @ W2b^T + b2 (round-2 proven) ----------------
__global__ __launch_bounds__(256) void gemm2_kernel(const ushort* __restrict__ A2,
                                                    const ushort* __restrict__ w2b,
                                                    const float* __restrict__ b2,
                                                    float* __restrict__ mem) {
    __shared__ ushort As[64][64];
    __shared__ ushort Bs[64][64];
    const int t = threadIdx.x;
    const int l = t & 63, wid = t >> 6;
    const int wr = wid >> 1, wc = wid & 1;
    const int mt = blockIdx.x >> 3, nt = blockIdx.x & 7;

    f32x4 acc[2][2] = {};
    const ushort* aG = A2  + (int64_t)(mt * 64) * POSEC;
    const ushort* bG = w2b + (int64_t)(nt * 64) * POSEC;
    const int srow = t >> 3, scol = (t & 7) * 8;
    const int fr = l & 15, fq = l >> 4;

    for (int k0 = 0; k0 < POSEC; k0 += 64) {
#pragma unroll
        for (int i = 0; i < 2; ++i) {
            gload_lds16(aG + (int64_t)(i * 32 + srow) * POSEC + k0 + scol,
                        (char*)&As[0][0] + i * 4096 + wid * 1024);
            gload_lds16(bG + (int64_t)(i * 32 + srow) * POSEC + k0 + scol,
                        (char*)&Bs[0][0] + i * 4096 + wid * 1024);
        }
        __syncthreads();
#pragma unroll
        for (int k2 = 0; k2 < 2; ++k2) {
            bf16x8 a[2], b[2];
#pragma unroll
            for (int m = 0; m < 2; ++m)
                a[m] = *(const bf16x8*)&As[wr * 32 + m * 16 + fr][k2 * 32 + fq * 8];
#pragma unroll
            for (int n = 0; n < 2; ++n)
                b[n] = *(const bf16x8*)&Bs[wc * 32 + n * 16 + fr][k2 * 32 + fq * 8];
#pragma unroll
            for (int m = 0; m < 2; ++m)
#pragma unroll
                for (int n = 0; n < 2; ++n)
                    acc[m][n] = __builtin_amdgcn_mfma_f32_16x16x32_bf16(a[m], b[n], acc[m][n], 0, 0, 0);
        }
        __syncthreads();
    }

    const int mbase = mt * 64 + wr * 32, nbase = nt * 64 + wc * 32;
#pragma unroll
    for (int m = 0; m < 2; ++m)
#pragma unroll
        for (int n = 0; n < 2; ++n) {
            int row0 = mbase + m * 16 + fq * 4;
            int col  = nbase + n * 16 + fr;
            float bias = b2[col];
#pragma unroll
            for (int r = 0; r < 4; ++r)
                mem[(int64_t)(row0 + r) * POSEC + col] = acc[m][n][r] + bias;
        }
}

// ---------------- score + sigmoid + blend + copy (round-2 + nt tail) ----------------
__global__ __launch_bounds__(256) void blend_kernel(const float* __restrict__ pred,
                                                    const float* __restrict__ mem,
                                                    float* __restrict__ out) {
    const int b = blockIdx.x;
    const int t = threadIdx.x;
    __shared__ float sm[POSEC];
    __shared__ float sg[CHUNKC];

    sm[t]       = mem[(int64_t)b * POSEC + t];
    sm[t + 256] = mem[(int64_t)b * POSEC + 256 + t];
    __syncthreads();

    const int l = t & 63, wid = t >> 6;
    const float4* sm4 = (const float4*)sm;
    const float4* p4 = (const float4*)pred + (int64_t)b * 16384;
    float4* o4 = (float4*)out + (int64_t)b * 16384;

#pragma unroll
    for (int ci = 0; ci < 8; ++ci) {
        int c = wid * 8 + ci;
        float4 h0 = p4[c * 128 + l * 2];
        float4 h1 = p4[c * 128 + l * 2 + 1];
        float4 m0 = sm4[l * 2];
        float4 m1 = sm4[l * 2 + 1];
        float s = h0.x * m0.x + h0.y * m0.y + h0.z * m0.z + h0.w * m0.w
                + h1.x * m1.x + h1.y * m1.y + h1.z * m1.z + h1.w * m1.w;
#pragma unroll
        for (int o = 32; o; o >>= 1) s += __shfl_xor(s, o);
        if (l == 0) sg[c] = 1.0f / (1.0f + expf(-s));
    }
    __syncthreads();

#pragma unroll
    for (int i = 0; i < 16; ++i) {
        int idx = i * 256 + t;
        int row = idx >> 7, c4 = idx & 127;
        float g = sg[row];
        float4 h = p4[idx];
        float4 m = sm4[c4];
        float4 r;
        r.x = g * h.x + (1.0f - g) * m.x;
        r.y = g * h.y + (1.0f - g) * m.y;
        r.z = g * h.z + (1.0f - g) * m.z;
        r.w = g * h.w + (1.0f - g) * m.w;
        o4[idx] = r;
    }
    // tail copy rows 32..127: one-touch stream, nontemporal
#pragma unroll
    for (int i = 0; i < 48; ++i) {
        int idx = 4096 + i * 256 + t;
        f4v h = __builtin_nontemporal_load((const f4v*)p4 + idx);
        __builtin_nontemporal_store(h, (f4v*)o4 + idx);
    }
}

// ---------------- launch ----------------

extern "C" void kernel_launch(void* const* d_in, const int* in_sizes, int n_in,
                              void* d_out, int out_size, void* d_ws, size_t ws_size,
                              hipStream_t stream) {
    const float* init = (const float*)d_in[0];
    const float* pred = (const float*)d_in[1];
    const float* W1   = (const float*)d_in[2];
    const float* b1   = (const float*)d_in[3];
    const float* W2   = (const float*)d_in[4];
    const float* b2   = (const float*)d_in[5];
    float* out = (float*)d_out;

    // KS=16 needs 157,810,688 B of ws; fall back to KS=8 (124,256,256 B) if short.
    const int KS = (ws_size >= 157810688u) ? 16 : 8;

    char* ws = (char*)d_ws;
    ushort* xb   = (ushort*)(ws);                               // 67108864 B
    ushort* w1b  = (ushort*)(ws + 67108864);                    // 16777216 B
    ushort* w2b  = (ushort*)(ws + 83886080);                    //   524288 B
    float*  part = (float*) (ws + 84410368);                    // KS*4194304 B
    char*   after = ws + 84410368 + (size_t)KS * 4194304;
    ushort* A2   = (ushort*)(after);                            //  2097152 B
    float*  mem  = (float*) (after + 2097152);                  //  4194304 B

    cvt_all_kernel<<<2560, 256, 0, stream>>>((const f4v*)init, (const f4v*)W1,
                                             (const f4v*)W2,
                                             (u16x4*)xb, (u16x4*)w1b, (u16x4*)w2b);
    if (KS == 16) {
        gemm1_kernel<16><<<256, 512, 0, stream>>>(xb, w1b, part);
        reduce_kernel<16><<<1024, 256, 0, stream>>>((const float4*)part, b1, (ushort4*)A2);
    } else {
        gemm1_kernel<8><<<128, 512, 0, stream>>>(xb, w1b, part);
        reduce_kernel<8><<<1024, 256, 0, stream>>>((const float4*)part, b1, (ushort4*)A2);
    }
    gemm2_kernel<<<256, 256, 0, stream>>>(A2, w2b, b2, mem);
    blend_kernel<<<NB, 256, 0, stream>>>(pred, mem, out);
}

// Round 9
// 312.455 us; speedup vs baseline: 1.2107x; 1.0550x over previous
//
#include <hip/hip_runtime.h>
#include <hip/hip_bf16.h>
#include <stdint.h>

#define CHUNKC 32
#define PRIORC 64
#define POSEC 512
#define PREDC 128
#define NB 2048
#define K1 (CHUNKC*POSEC)   // 16384
#define KS 16               // split-K factor (bf16 partials -> fits proven ws budget)
#define KCH (K1/KS)         // 1024

typedef __attribute__((ext_vector_type(8))) short bf16x8;
typedef __attribute__((ext_vector_type(8))) unsigned short u16x8;
typedef __attribute__((ext_vector_type(4))) float f32x4;
typedef __attribute__((ext_vector_type(4))) float f4v;
typedef __attribute__((ext_vector_type(4))) unsigned short u16x4;

__device__ __forceinline__ unsigned short f2b(float f) {
    union { float f; unsigned int u; } x; x.f = f;
    unsigned int r = x.u + 0x7fffu + ((x.u >> 16) & 1u);
    return (unsigned short)(r >> 16);
}
__device__ __forceinline__ float b2f(unsigned short u) {
    union { unsigned int i; float f; } x; x.i = ((unsigned int)u) << 16; return x.f;
}

__device__ __forceinline__ void gload_lds16(const void* g, void* l) {
    __builtin_amdgcn_global_load_lds(
        (const __attribute__((address_space(1))) unsigned int*)g,
        (__attribute__((address_space(3))) unsigned int*)l, 16, 0, 0);
}

// ---------------- cvt_all: x-slice, W1, W2 -> bf16 (nontemporal streams) ----------------
#define XN4   8388608   // 2048*4096 float4 of x-slice
#define W1N4  2097152   // 512*16384/4
#define W2N4  65536     // 512*512/4
__global__ __launch_bounds__(256) void cvt_all_kernel(const f4v* __restrict__ init,
                                                      const f4v* __restrict__ W1,
                                                      const f4v* __restrict__ W2,
                                                      u16x4* __restrict__ xb,
                                                      u16x4* __restrict__ w1b,
                                                      u16x4* __restrict__ w2b) {
    const int64_t n = XN4 + W1N4 + W2N4;
    const int64_t stride = (int64_t)gridDim.x * blockDim.x;
    for (int64_t i = (int64_t)blockIdx.x * blockDim.x + threadIdx.x; i < n; i += stride) {
        f4v v; u16x4* dst;
        if (i < XN4) {
            int64_t b = i >> 12, r = i & 4095;
            v = __builtin_nontemporal_load(init + b * 8192 + 4096 + r);
            dst = xb + i;
        } else if (i < XN4 + W1N4) {
            v = __builtin_nontemporal_load(W1 + (i - XN4));
            dst = w1b + (i - XN4);
        } else {
            v = __builtin_nontemporal_load(W2 + (i - XN4 - W1N4));
            dst = w2b + (i - XN4 - W1N4);
        }
        u16x4 o;
        o[0] = f2b(v[0]); o[1] = f2b(v[1]); o[2] = f2b(v[2]); o[3] = f2b(v[3]);
        __builtin_nontemporal_store(o, dst);
    }
}

// ---------------- GEMM1: bf16 partials of x @ W1^T ----------------
// 256x256 tile, BK=64, 8 waves (2x4; wave owns 128x64), gload_lds both operands.
// 2-phase dbuf (round-8) + T2 XOR-swizzle (rule #21): linear LDS dest,
// inverse-swizzled GLOBAL source column-slot, swizzled read column-slot.
// grid = 8 mt * 2 nt * 16 ks = 256 blocks; XCD-chunked bijective swizzle.
__global__ __launch_bounds__(512) void gemm1_kernel(const ushort* __restrict__ xb,
                                                    const ushort* __restrict__ w1b,
                                                    ushort* __restrict__ part) {
    __shared__ ushort As[2][256][64];   // 2 x 32 KB
    __shared__ ushort Bs[2][256][64];   // 2 x 32 KB
    const int t = threadIdx.x;
    const int l = t & 63, wid = t >> 6;
    const int wr = wid >> 2, wc = wid & 3;          // 2x4 waves; wave owns 128x64
    const int cpx = 256 >> 3;
    const int orig = (blockIdx.x & 7) * cpx + (blockIdx.x >> 3);
    const int mt = orig & 7, nt = (orig >> 3) & 1, ks = orig >> 4;
    const int NIT = KCH / 64;                       // 16

    f32x4 acc[8][4] = {};

    const ushort* aG = xb  + (int64_t)(mt * 256) * K1 + ks * KCH;
    const ushort* bG = w1b + (int64_t)(nt * 256) * K1 + ks * KCH;
    const int srow = t >> 3;
    // T2: source col-slot XORed with dest-row&7 ( == (t>>3)&7 ); dest stays lane-linear
    const int scol = (((t & 7) ^ ((t >> 3) & 7))) * 8;

    const int fr = l & 15, fq = l >> 4;
    const int cx = fr & 7;                          // read-side swizzle key

    // prologue: stage tile 0 into buffer 0
#pragma unroll
    for (int i = 0; i < 4; ++i) {
        gload_lds16(aG + (int64_t)(i * 64 + srow) * K1 + scol,
                    (char*)&As[0][0][0] + i * 8192 + wid * 1024);
        gload_lds16(bG + (int64_t)(i * 64 + srow) * K1 + scol,
                    (char*)&Bs[0][0][0] + i * 8192 + wid * 1024);
    }

    for (int it = 0; it < NIT; ++it) {
        const int cur = it & 1;
        __syncthreads();    // drains buf[cur]'s loads (issued one full iter ago)
        if (it + 1 < NIT) {
            const int nxt = cur ^ 1;
            const int k0 = (it + 1) * 64;
#pragma unroll
            for (int i = 0; i < 4; ++i) {
                gload_lds16(aG + (int64_t)(i * 64 + srow) * K1 + k0 + scol,
                            (char*)&As[nxt][0][0] + i * 8192 + wid * 1024);
                gload_lds16(bG + (int64_t)(i * 64 + srow) * K1 + k0 + scol,
                            (char*)&Bs[nxt][0][0] + i * 8192 + wid * 1024);
            }
        }
#pragma unroll
        for (int k2 = 0; k2 < 2; ++k2) {
            const int cs = ((k2 * 4 + fq) ^ cx) * 8;    // swizzled col byte-slot
            bf16x8 a[8], b[4];
#pragma unroll
            for (int m = 0; m < 8; ++m)
                a[m] = *(const bf16x8*)&As[cur][wr * 128 + m * 16 + fr][cs];
#pragma unroll
            for (int n = 0; n < 4; ++n)
                b[n] = *(const bf16x8*)&Bs[cur][wc * 64 + n * 16 + fr][cs];
#pragma unroll
            for (int m = 0; m < 8; ++m)
#pragma unroll
                for (int n = 0; n < 4; ++n)
                    acc[m][n] = __builtin_amdgcn_mfma_f32_16x16x32_bf16(a[m], b[n], acc[m][n], 0, 0, 0);
        }
    }

    ushort* P = part + (int64_t)ks * NB * POSEC;
    const int mbase = mt * 256 + wr * 128, nbase = nt * 256 + wc * 64;
#pragma unroll
    for (int m = 0; m < 8; ++m)
#pragma unroll
        for (int n = 0; n < 4; ++n) {
            int row0 = mbase + m * 16 + fq * 4;
            int col  = nbase + n * 16 + fr;
#pragma unroll
            for (int r = 0; r < 4; ++r)
                P[(int64_t)(row0 + r) * POSEC + col] = f2b(acc[m][n][r]);
        }
}

// ---------------- reduce: A2 = bf16(sum_ks bf16part + b1) ----------------
__global__ __launch_bounds__(256) void reduce_kernel(const ushort* __restrict__ part,
                                                     const float* __restrict__ b1,
                                                     u16x8* __restrict__ A2) {
    const int gid = blockIdx.x * 256 + threadIdx.x;     // 131072 threads, 8 elems each
    const int64_t e0 = (int64_t)gid * 8;
    float s[8] = {};
#pragma unroll
    for (int k = 0; k < KS; ++k) {
        u16x8 p = *(const u16x8*)(part + (int64_t)k * (NB * POSEC) + e0);
#pragma unroll
        for (int j = 0; j < 8; ++j) s[j] += b2f(p[j]);
    }
    const int col = (int)(e0 & 511);
    f4v b0 = *(const f4v*)&b1[col];
    f4v b4 = *(const f4v*)&b1[col + 4];
    u16x8 o;
#pragma unroll
    for (int j = 0; j < 4; ++j) { o[j] = f2b(s[j] + b0[j]); o[j+4] = f2b(s[j+4] + b4[j]); }
    A2[gid] = o;
}

// ---------------- GEMM2: mem = A2 @ W2b^T + b2 (round-2 + T2 swizzle) ----------------
__global__ __launch_bounds__(256) void gemm2_kernel(const ushort* __restrict__ A2,
                                                    const ushort* __restrict__ w2b,
                                                    const float* __restrict__ b2,
                                                    float* __restrict__ mem) {
    __shared__ ushort As[64][64];
    __shared__ ushort Bs[64][64];
    const int t = threadIdx.x;
    const int l = t & 63, wid = t >> 6;
    const int wr = wid >> 1, wc = wid & 1;
    const int mt = blockIdx.x >> 3, nt = blockIdx.x & 7;

    f32x4 acc[2][2] = {};
    const ushort* aG = A2  + (int64_t)(mt * 64) * POSEC;
    const ushort* bG = w2b + (int64_t)(nt * 64) * POSEC;
    const int srow = t >> 3;
    const int scol = (((t & 7) ^ ((t >> 3) & 7))) * 8;
    const int fr = l & 15, fq = l >> 4;
    const int cx = fr & 7;

    for (int k0 = 0; k0 < POSEC; k0 += 64) {
#pragma unroll
        for (int i = 0; i < 2; ++i) {
            gload_lds16(aG + (int64_t)(i * 32 + srow) * POSEC + k0 + scol,
                        (char*)&As[0][0] + i * 4096 + wid * 1024);
            gload_lds16(bG + (int64_t)(i * 32 + srow) * POSEC + k0 + scol,
                        (char*)&Bs[0][0] + i * 4096 + wid * 1024);
        }
        __syncthreads();
#pragma unroll
        for (int k2 = 0; k2 < 2; ++k2) {
            const int cs = ((k2 * 4 + fq) ^ cx) * 8;
            bf16x8 a[2], b[2];
#pragma unroll
            for (int m = 0; m < 2; ++m)
                a[m] = *(const bf16x8*)&As[wr * 32 + m * 16 + fr][cs];
#pragma unroll
            for (int n = 0; n < 2; ++n)
                b[n] = *(const bf16x8*)&Bs[wc * 32 + n * 16 + fr][cs];
#pragma unroll
            for (int m = 0; m < 2; ++m)
#pragma unroll
                for (int n = 0; n < 2; ++n)
                    acc[m][n] = __builtin_amdgcn_mfma_f32_16x16x32_bf16(a[m], b[n], acc[m][n], 0, 0, 0);
        }
        __syncthreads();
    }

    const int mbase = mt * 64 + wr * 32, nbase = nt * 64 + wc * 32;
#pragma unroll
    for (int m = 0; m < 2; ++m)
#pragma unroll
        for (int n = 0; n < 2; ++n) {
            int row0 = mbase + m * 16 + fq * 4;
            int col  = nbase + n * 16 + fr;
            float bias = b2[col];
#pragma unroll
            for (int r = 0; r < 4; ++r)
                mem[(int64_t)(row0 + r) * POSEC + col] = acc[m][n][r] + bias;
        }
}

// ---------------- score + sigmoid + blend + copy (round-2 + nt tail) ----------------
__global__ __launch_bounds__(256) void blend_kernel(const float* __restrict__ pred,
                                                    const float* __restrict__ mem,
                                                    float* __restrict__ out) {
    const int b = blockIdx.x;
    const int t = threadIdx.x;
    __shared__ float sm[POSEC];
    __shared__ float sg[CHUNKC];

    sm[t]       = mem[(int64_t)b * POSEC + t];
    sm[t + 256] = mem[(int64_t)b * POSEC + 256 + t];
    __syncthreads();

    const int l = t & 63, wid = t >> 6;
    const float4* sm4 = (const float4*)sm;
    const float4* p4 = (const float4*)pred + (int64_t)b * 16384;
    float4* o4 = (float4*)out + (int64_t)b * 16384;

#pragma unroll
    for (int ci = 0; ci < 8; ++ci) {
        int c = wid * 8 + ci;
        float4 h0 = p4[c * 128 + l * 2];
        float4 h1 = p4[c * 128 + l * 2 + 1];
        float4 m0 = sm4[l * 2];
        float4 m1 = sm4[l * 2 + 1];
        float s = h0.x * m0.x + h0.y * m0.y + h0.z * m0.z + h0.w * m0.w
                + h1.x * m1.x + h1.y * m1.y + h1.z * m1.z + h1.w * m1.w;
#pragma unroll
        for (int o = 32; o; o >>= 1) s += __shfl_xor(s, o);
        if (l == 0) sg[c] = 1.0f / (1.0f + expf(-s));
    }
    __syncthreads();

#pragma unroll
    for (int i = 0; i < 16; ++i) {
        int idx = i * 256 + t;
        int row = idx >> 7, c4 = idx & 127;
        float g = sg[row];
        float4 h = p4[idx];
        float4 m = sm4[c4];
        float4 r;
        r.x = g * h.x + (1.0f - g) * m.x;
        r.y = g * h.y + (1.0f - g) * m.y;
        r.z = g * h.z + (1.0f - g) * m.z;
        r.w = g * h.w + (1.0f - g) * m.w;
        o4[idx] = r;
    }
#pragma unroll
    for (int i = 0; i < 48; ++i) {
        int idx = 4096 + i * 256 + t;
        f4v h = __builtin_nontemporal_load((const f4v*)p4 + idx);
        __builtin_nontemporal_store(h, (f4v*)o4 + idx);
    }
}

// ---------------- launch ----------------

extern "C" void kernel_launch(void* const* d_in, const int* in_sizes, int n_in,
                              void* d_out, int out_size, void* d_ws, size_t ws_size,
                              hipStream_t stream) {
    const float* init = (const float*)d_in[0];
    const float* pred = (const float*)d_in[1];
    const float* W1   = (const float*)d_in[2];
    const float* b1   = (const float*)d_in[3];
    const float* W2   = (const float*)d_in[4];
    const float* b2   = (const float*)d_in[5];
    float* out = (float*)d_out;

    char* ws = (char*)d_ws;
    ushort* xb   = (ushort*)(ws);                       // 67108864 B
    ushort* w1b  = (ushort*)(ws + 67108864);            // 16777216 B
    ushort* w2b  = (ushort*)(ws + 83886080);            //   524288 B
    ushort* part = (ushort*)(ws + 84410368);            // 33554432 B (16 x 2048x512 bf16)
    ushort* A2   = (ushort*)(ws + 117964800);           //  2097152 B
    float*  mem  = (float*) (ws + 120061952);           //  4194304 B
    // total 124,256,256 B == round-2 proven footprint

    cvt_all_kernel<<<2560, 256, 0, stream>>>((const f4v*)init, (const f4v*)W1,
                                             (const f4v*)W2,
                                             (u16x4*)xb, (u16x4*)w1b, (u16x4*)w2b);
    gemm1_kernel<<<256, 512, 0, stream>>>(xb, w1b, part);
    reduce_kernel<<<512, 256, 0, stream>>>(part, b1, (u16x8*)A2);
    gemm2_kernel<<<256, 256, 0, stream>>>(A2, w2b, b2, mem);
    blend_kernel<<<NB, 256, 0, stream>>>(pred, mem, out);
}